// Round 10
// baseline (1175.616 us; speedup 1.0000x reference)
//
#include <hip/hip_runtime.h>

#define HALO 10
#define NIMG 48                 // 16 batch * 3 channels
#define NBLK 1280               // 5 blocks/CU * 256 CUs — exactly co-resident

// Gaussian(sigma=1.5, 11 taps), normalized (computed offline in double).
#define GWLIST { 0.0010284f, 0.0075987f, 0.0360008f, 0.1093607f, 0.2130056f, \
                 0.2660117f, 0.2130056f, 0.1093607f, 0.0360008f, 0.0075987f, 0.0010284f }

// ---- mfma-path LDS layout (fp16, pitch 56 halves = 112 B) -----------------
#define PP   56
#define PSZ  (48 * 56)          // plane = 2688 fp16
#define HTP  56
#define HTSZ (32 * 56)          // h_T plane = 1792 fp16
#define WT0  (5 * PSZ)          // wfrag table at halves 13440 (byte 26880)
// ---- scalar-path LDS layout (fp32) ----------------------------------------
#define SSTR 32
#define SQP  (42 * 32)          // per-quantity plane = 1344 floats (5*SQP*4 = 26880 B)
// ---- shared smem budget ----------------------------------------------------
#define RED_OFF 27904           // red float[16] lives here (past both layouts)
#define SMBYTES 27968           // 27968*5 = 139840 <= 163840 -> 5 blocks/CU

typedef _Float16 half8 __attribute__((ext_vector_type(8)));
typedef _Float16 half4 __attribute__((ext_vector_type(4)));
typedef float    floatx4 __attribute__((ext_vector_type(4)));

// ---------------------------------------------------------------------------
// Device-scope grid barrier (all NBLK blocks co-resident by construction).
// Generation-based: read gen, arrive, last arriver resets ctr then bumps gen
// (release); spinners acquire-load gen. __threadfence = agent fence handles
// cross-XCD L2 visibility of the plain pool/partial stores.
__device__ __forceinline__ void grid_sync(unsigned* ctr, unsigned* gen) {
    __syncthreads();
    if (threadIdx.x == 0) {
        __threadfence();
        unsigned g = __hip_atomic_load(gen, __ATOMIC_ACQUIRE, __HIP_MEMORY_SCOPE_AGENT);
        unsigned a = __hip_atomic_fetch_add(ctr, 1u, __ATOMIC_ACQ_REL, __HIP_MEMORY_SCOPE_AGENT);
        if (a == NBLK - 1) {
            __hip_atomic_store(ctr, 0u, __ATOMIC_RELAXED, __HIP_MEMORY_SCOPE_AGENT);
            __hip_atomic_fetch_add(gen, 1u, __ATOMIC_ACQ_REL, __HIP_MEMORY_SCOPE_AGENT);
        } else {
            while (__hip_atomic_load(gen, __ATOMIC_ACQUIRE, __HIP_MEMORY_SCOPE_AGENT) == g)
                __builtin_amdgcn_s_sleep(2);
        }
        __threadfence();
    }
    __syncthreads();
}

// ---------------------------------------------------------------------------
// MFMA tile (scales 0,1) — body identical to R9's proven kernel.
template <bool FUSE>
__device__ __forceinline__ void mfma_tile(
    const float* __restrict__ A, const float* __restrict__ B, int H,
    int bx, int by, int z, float2* __restrict__ partial, int g,
    float* __restrict__ poolA, float* __restrict__ poolB,
    _Float16* sm, float* red, const half8 wfrag, const float* w)
{
    const int W = H;
    const int tid  = threadIdx.x;
    const int lane = tid & 63;
    const int wv   = tid >> 6;
    const int gx0  = bx * 32;
    const int gy0  = by * 32;
    const float* a = A + (size_t)z * H * W;
    const float* b = B + (size_t)z * H * W;

    // stage 1: 48x48 region -> 5 fp16 quantity planes
    const bool fast = (gy0 + 48 <= H) && (gx0 + 48 <= W);
    for (int e = tid; e < 288; e += 256) {
        int r = e / 6, c8 = e - r * 6;
        float fa[8], fb[8];
        if (fast) {
            const float* pa = a + (size_t)(gy0 + r) * W + gx0 + c8 * 8;
            const float* pb = b + (size_t)(gy0 + r) * W + gx0 + c8 * 8;
            *(float4*)&fa[0] = *(const float4*)pa;
            *(float4*)&fa[4] = *(const float4*)(pa + 4);
            *(float4*)&fb[0] = *(const float4*)pb;
            *(float4*)&fb[4] = *(const float4*)(pb + 4);
        } else {
            int gy = gy0 + r;
            #pragma unroll
            for (int i = 0; i < 8; ++i) {
                int gx = gx0 + c8 * 8 + i;
                bool ok = (gy < H) && (gx < W);
                size_t idx = (size_t)gy * W + gx;
                fa[i] = ok ? a[idx] : 0.f;
                fb[i] = ok ? b[idx] : 0.f;
            }
        }
        half8 ha, hb;
        #pragma unroll
        for (int i = 0; i < 8; ++i) {
            ha[i] = (_Float16)fa[i];
            hb[i] = (_Float16)fb[i];
        }
        half8 haa = ha * ha;
        half8 hbb = hb * hb;
        half8 hab = ha * hb;
        int o = r * PP + c8 * 8;
        *(half8*)&sm[o + 0 * PSZ] = ha;
        *(half8*)&sm[o + 1 * PSZ] = hb;
        *(half8*)&sm[o + 2 * PSZ] = haa;
        *(half8*)&sm[o + 3 * PSZ] = hbb;
        *(half8*)&sm[o + 4 * PSZ] = hab;
    }
    __syncthreads();

    // stage 2a: h-conv via MFMA, results in registers
    half4 res[8];
    {
        const int arow = (lane & 15) * PP + ((lane >> 4) << 3);
        #pragma unroll
        for (int u = 0; u < 8; ++u) {
            int jj = wv + 4 * u;
            if (jj < 30) {
                int q = jj / 6, rem = jj - q * 6;
                int m0 = (rem >> 1) << 4;
                int x0 = (rem & 1) << 4;
                half8 afrag = *(const half8*)&sm[q * PSZ + m0 * PP + x0 + arow];
                floatx4 c = {0.f, 0.f, 0.f, 0.f};
                c = __builtin_amdgcn_mfma_f32_16x16x32_f16(afrag, wfrag, c, 0, 0, 0);
                half4 hv;
                hv[0] = (_Float16)c[0]; hv[1] = (_Float16)c[1];
                hv[2] = (_Float16)c[2]; hv[3] = (_Float16)c[3];
                res[u] = hv;
            }
        }
    }
    __syncthreads();

    // stage 2b: write transposed fp16 h_T into dead plane region
    {
        const int crow = (lane & 15) * HTP + ((lane >> 4) << 2);
        #pragma unroll
        for (int u = 0; u < 8; ++u) {
            int jj = wv + 4 * u;
            if (jj < 30) {
                int q = jj / 6, rem = jj - q * 6;
                int m0 = (rem >> 1) << 4;
                int x0 = (rem & 1) << 4;
                *(half4*)&sm[q * HTSZ + x0 * HTP + m0 + crow] = res[u];
            }
        }
    }
    __syncthreads();

    // stage 3: v-conv via MFMA + SSIM
    float csSum = 0.f, ssimSum = 0.f;
    {
        const int y0 = (wv >> 1) << 4;
        const int x0 = (wv & 1) << 4;
        const int brow = (lane & 15) * HTP + ((lane >> 4) << 3);
        floatx4 m[5];
        #pragma unroll
        for (int q = 0; q < 5; ++q) {
            half8 bfrag = *(const half8*)&sm[q * HTSZ + x0 * HTP + y0 + brow];
            floatx4 c = {0.f, 0.f, 0.f, 0.f};
            m[q] = __builtin_amdgcn_mfma_f32_16x16x32_f16(wfrag, bfrag, c, 0, 0, 0);
        }
        const int OH = H - HALO, OW = W - HALO;
        const int gx  = gx0 + x0 + (lane & 15);
        const int gyb = gy0 + y0 + ((lane >> 4) << 2);
        const float C1 = 1e-4f;
        const float C2 = 9e-4f;
        if (gx < OW) {
            #pragma unroll
            for (int i = 0; i < 4; ++i) {
                int gy = gyb + i;
                if (gy < OH) {
                    float mu1 = m[0][i], mu2 = m[1][i];
                    float s1sq = m[2][i] - mu1 * mu1;
                    float s2sq = m[3][i] - mu2 * mu2;
                    float s12  = m[4][i] - mu1 * mu2;
                    float denom = s1sq + s2sq + C2;
                    float num   = 2.f * s12 + C2;
                    float csv = num * __frcp_rn(denom);
                    float ssv = csv * (2.f * mu1 * mu2 + C1) *
                                __frcp_rn(mu1 * mu1 + mu2 * mu2 + C1);
                    csSum   += csv;
                    ssimSum += ssv;
                }
            }
        }
    }

    // block reduction -> partial slot
    #pragma unroll
    for (int off = 32; off > 0; off >>= 1) {
        csSum   += __shfl_down(csSum, off, 64);
        ssimSum += __shfl_down(ssimSum, off, 64);
    }
    if (lane == 0) {
        red[wv]     = csSum;
        red[8 + wv] = ssimSum;
    }
    __syncthreads();
    if (tid == 0) {
        float c = 0.f, s = 0.f;
        #pragma unroll
        for (int i = 0; i < 4; ++i) { c += red[i]; s += red[8 + i]; }
        partial[(z * g + by) * g + bx] = make_float2(c, s);
    }

    // fused 2x2 avg-pool of own 32x32 region
    if (FUSE && tid < 128) {
        const int OH2 = H >> 1, OW2 = W >> 1;
        const int img = tid >> 6;
        const int rem = tid & 63;
        const int pr  = rem >> 2;
        const int pq  = rem & 3;
        const float* src = img ? b : a;
        float* dst = (img ? poolB : poolA) + (size_t)z * OH2 * OW2;
        size_t base = (size_t)(gy0 + 2 * pr) * W + gx0 + pq * 8;
        float4 r0 = *(const float4*)(src + base);
        float4 r1 = *(const float4*)(src + base + 4);
        float4 r2 = *(const float4*)(src + base + W);
        float4 r3 = *(const float4*)(src + base + W + 4);
        float4 o;
        o.x = 0.25f * (r0.x + r0.y + r2.x + r2.y);
        o.y = 0.25f * (r0.z + r0.w + r2.z + r2.w);
        o.z = 0.25f * (r1.x + r1.y + r3.x + r3.y);
        o.w = 0.25f * (r1.z + r1.w + r3.z + r3.w);
        *(float4*)(dst + (size_t)((gy0 >> 1) + pr) * OW2 + (gx0 >> 1) + pq * 4) = o;
    }
}

// ---------------------------------------------------------------------------
// Exact fp32 scalar tile (scales 2-4) — body identical to R9's kernel.
template <bool FUSE>
__device__ __forceinline__ void scalar_tile(
    const float* __restrict__ A, const float* __restrict__ B, int H,
    int bx, int by, int z, float2* __restrict__ partial, int g,
    float* __restrict__ poolA, float* __restrict__ poolB,
    float* lds, float* red, const float* w)
{
    const int W = H;
    const int tid = threadIdx.x;
    const int gx0 = bx * 32;
    const int gy0 = by * 32;
    const float* a = A + (size_t)z * H * W;
    const float* b = B + (size_t)z * H * W;

    const bool fast = (gy0 + 42 <= H) && (gx0 + 44 <= W);
    for (int e = tid; e < 42 * 8; e += 256) {
        int r = e >> 3, c0 = (e & 7) * 4;
        int gy = gy0 + r;
        float s1[4]  = {0.f, 0.f, 0.f, 0.f};
        float s2[4]  = {0.f, 0.f, 0.f, 0.f};
        float s11[4] = {0.f, 0.f, 0.f, 0.f};
        float s22[4] = {0.f, 0.f, 0.f, 0.f};
        float s12[4] = {0.f, 0.f, 0.f, 0.f};
        #pragma unroll
        for (int c = 0; c < 4; ++c) {
            float ea[4], eb[4];
            if (fast) {
                const float* pa = a + (size_t)gy * W + gx0 + c0 + 4 * c;
                const float* pb = b + (size_t)gy * W + gx0 + c0 + 4 * c;
                *(float4*)&ea[0] = *(const float4*)pa;
                *(float4*)&eb[0] = *(const float4*)pb;
            } else {
                #pragma unroll
                for (int t = 0; t < 4; ++t) {
                    int gx = gx0 + c0 + 4 * c + t;
                    bool ok = (gy < H) && (gx < W);
                    size_t idx = (size_t)gy * W + gx;
                    ea[t] = ok ? a[idx] : 0.f;
                    eb[t] = ok ? b[idx] : 0.f;
                }
            }
            #pragma unroll
            for (int mm = 0; mm < 4; ++mm) {
                const int i = 4 * c + mm;
                float va = ea[mm], vb = eb[mm];
                float vaa = va * va, vbb = vb * vb, vab = va * vb;
                #pragma unroll
                for (int k = 0; k < 4; ++k) {
                    const int j = i - k;
                    if (j >= 0 && j <= 10) {
                        float wj = w[j];
                        s1[k]  += wj * va;
                        s2[k]  += wj * vb;
                        s11[k] += wj * vaa;
                        s22[k] += wj * vbb;
                        s12[k] += wj * vab;
                    }
                }
            }
        }
        int hb = r * SSTR + c0;
        *(float4*)&lds[hb + 0 * SQP] = make_float4(s1[0],  s1[1],  s1[2],  s1[3]);
        *(float4*)&lds[hb + 1 * SQP] = make_float4(s2[0],  s2[1],  s2[2],  s2[3]);
        *(float4*)&lds[hb + 2 * SQP] = make_float4(s11[0], s11[1], s11[2], s11[3]);
        *(float4*)&lds[hb + 3 * SQP] = make_float4(s22[0], s22[1], s22[2], s22[3]);
        *(float4*)&lds[hb + 4 * SQP] = make_float4(s12[0], s12[1], s12[2], s12[3]);
    }
    __syncthreads();

    const float C1 = 1e-4f;
    const float C2 = 9e-4f;
    float csSum = 0.f, ssimSum = 0.f;
    {
        const int ox  = tid & 31;
        const int oy0 = (tid >> 5) * 4;
        float m[5][4];
        #pragma unroll
        for (int q = 0; q < 5; ++q) {
            const float* hq = &lds[q * SQP + oy0 * SSTR + ox];
            float win[14];
            #pragma unroll
            for (int i = 0; i < 14; ++i) win[i] = hq[i * SSTR];
            #pragma unroll
            for (int k = 0; k < 4; ++k) {
                float acc = 0.f;
                #pragma unroll
                for (int j = 0; j < 11; ++j) acc += w[j] * win[k + j];
                m[q][k] = acc;
            }
        }
        const int OH = H - HALO, OW = W - HALO;
        const int gx = gx0 + ox;
        #pragma unroll
        for (int k = 0; k < 4; ++k) {
            int gy = gy0 + oy0 + k;
            if (gy < OH && gx < OW) {
                float mu1 = m[0][k], mu2 = m[1][k];
                float s1sq = m[2][k] - mu1 * mu1;
                float s2sq = m[3][k] - mu2 * mu2;
                float s12  = m[4][k] - mu1 * mu2;
                float denom  = s1sq + s2sq + C2;
                float num_cs = 2.f * s12 + C2;
                float csv = num_cs * __frcp_rn(denom);
                float ssv = csv * (2.f * mu1 * mu2 + C1) *
                            __frcp_rn(mu1 * mu1 + mu2 * mu2 + C1);
                csSum   += csv;
                ssimSum += ssv;
            }
        }
    }

    #pragma unroll
    for (int off = 32; off > 0; off >>= 1) {
        csSum   += __shfl_down(csSum, off, 64);
        ssimSum += __shfl_down(ssimSum, off, 64);
    }
    int wave = tid >> 6, lane = tid & 63;
    if (lane == 0) {
        red[wave]     = csSum;
        red[8 + wave] = ssimSum;
    }
    __syncthreads();
    if (tid == 0) {
        float c = 0.f, s = 0.f;
        #pragma unroll
        for (int i = 0; i < 4; ++i) { c += red[i]; s += red[8 + i]; }
        partial[(z * g + by) * g + bx] = make_float2(c, s);
    }

    if (FUSE && tid < 128) {
        const int OH2 = H >> 1, OW2 = W >> 1;
        const int img = tid >> 6;
        const int rem = tid & 63;
        const int pr  = rem >> 2;
        const int pq  = rem & 3;
        const float* src = img ? b : a;
        float* dst = (img ? poolB : poolA) + (size_t)z * OH2 * OW2;
        size_t base = (size_t)(gy0 + 2 * pr) * W + gx0 + pq * 8;
        float4 r0 = *(const float4*)(src + base);
        float4 r1 = *(const float4*)(src + base + 4);
        float4 r2 = *(const float4*)(src + base + W);
        float4 r3 = *(const float4*)(src + base + W + 4);
        float4 o;
        o.x = 0.25f * (r0.x + r0.y + r2.x + r2.y);
        o.y = 0.25f * (r0.z + r0.w + r2.z + r2.w);
        o.z = 0.25f * (r1.x + r1.y + r3.x + r3.y);
        o.w = 0.25f * (r1.z + r1.w + r3.z + r3.w);
        *(float4*)(dst + (size_t)((gy0 >> 1) + pr) * OW2 + (gx0 >> 1) + pq * 4) = o;
    }
}

// ---------------------------------------------------------------------------
// One persistent kernel: all 5 scales + final combine, grid-sync between.
__global__ __launch_bounds__(256, 5) void ms_ssim_all(
    const float* __restrict__ A0, const float* __restrict__ B0,
    float* __restrict__ out, unsigned char* __restrict__ ws)
{
    __shared__ __align__(16) unsigned char smem[SMBYTES];
    _Float16* sm  = (_Float16*)smem;
    float*    lds = (float*)smem;
    float*    red = (float*)(smem + RED_OFF);

    unsigned* ctr = (unsigned*)ws;                 // zeroed by hipMemsetAsync
    unsigned* gen = (unsigned*)(ws + 128);
    float2* partial = (float2*)(ws + 1024);        // 16368 slots
    float* pyr = (float*)(ws + (1 << 18));
    float* pa1 = pyr;
    float* pb1 = pa1 + (size_t)NIMG * 256 * 256;
    float* pa2 = pb1 + (size_t)NIMG * 256 * 256;
    float* pb2 = pa2 + (size_t)NIMG * 128 * 128;
    float* pa3 = pb2 + (size_t)NIMG * 128 * 128;
    float* pb3 = pa3 + (size_t)NIMG * 64 * 64;
    float* pa4 = pb3 + (size_t)NIMG * 64 * 64;
    float* pb4 = pa4 + (size_t)NIMG * 32 * 32;

    const float w[11] = GWLIST;
    const int tid = threadIdx.x;

    // band-weight fragment table: built once, read once into registers
    if (tid < 64) {
        int base = ((tid >> 4) << 3) - (tid & 15);
        half8 wf;
        #pragma unroll
        for (int i = 0; i < 8; ++i) {
            int j = base + i;
            float v = 0.f;
            #pragma unroll
            for (int J = 0; J < 11; ++J) v = (j == J) ? w[J] : v;
            wf[i] = (_Float16)v;
        }
        *(half8*)&sm[WT0 + tid * 8] = wf;
    }
    __syncthreads();
    const half8 wfrag = *(const half8*)&sm[WT0 + (tid & 63) * 8];
    __syncthreads();

    // ---- scale 0 (512): 12288 tiles ------------------------------------
    for (unsigned t = blockIdx.x; t < 12288; t += NBLK) {
        int z = t >> 8, by = (t >> 4) & 15, bx = t & 15;
        mfma_tile<true>(A0, B0, 512, bx, by, z, partial, 16, pa1, pb1,
                        sm, red, wfrag, w);
    }
    grid_sync(ctr, gen);
    // ---- scale 1 (256): 3072 tiles -------------------------------------
    for (unsigned t = blockIdx.x; t < 3072; t += NBLK) {
        int z = t >> 6, by = (t >> 3) & 7, bx = t & 7;
        mfma_tile<true>(pa1, pb1, 256, bx, by, z, partial + 12288, 8, pa2, pb2,
                        sm, red, wfrag, w);
    }
    grid_sync(ctr, gen);
    // ---- scale 2 (128): 768 tiles, exact fp32 --------------------------
    for (unsigned t = blockIdx.x; t < 768; t += NBLK) {
        int z = t >> 4, by = (t >> 2) & 3, bx = t & 3;
        scalar_tile<true>(pa2, pb2, 128, bx, by, z, partial + 15360, 4, pa3, pb3,
                          lds, red, w);
    }
    grid_sync(ctr, gen);
    // ---- scale 3 (64): 192 tiles ---------------------------------------
    for (unsigned t = blockIdx.x; t < 192; t += NBLK) {
        int z = t >> 2, by = (t >> 1) & 1, bx = t & 1;
        scalar_tile<true>(pa3, pb3, 64, bx, by, z, partial + 16128, 2, pa4, pb4,
                          lds, red, w);
    }
    grid_sync(ctr, gen);
    // ---- scale 4 (32): 48 tiles, no pool -------------------------------
    for (unsigned t = blockIdx.x; t < 48; t += NBLK) {
        scalar_tile<false>(pa4, pb4, 32, 0, 0, (int)t, partial + 16320, 1,
                           nullptr, nullptr, lds, red, w);
    }
    grid_sync(ctr, gen);

    // ---- final combine: block 0 only -----------------------------------
    if (blockIdx.x == 0) {
        double* dred = (double*)smem;              // 8 doubles
        double* resC = (double*)(smem + 64);       // 5 doubles
        double* resS = (double*)(smem + 128);      // 5 doubles
        const int segs[6] = {0, 12288, 15360, 16128, 16320, 16368};
        for (int s = 0; s < 5; ++s) {
            double c = 0.0, v = 0.0;
            #pragma unroll 4
            for (int i = segs[s] + tid; i < segs[s + 1]; i += 256) {
                float2 p = partial[i];
                c += (double)p.x;
                v += (double)p.y;
            }
            #pragma unroll
            for (int off = 32; off > 0; off >>= 1) {
                c += __shfl_down(c, off, 64);
                v += __shfl_down(v, off, 64);
            }
            int wave = tid >> 6, lane = tid & 63;
            __syncthreads();
            if (lane == 0) { dred[wave] = c; dred[4 + wave] = v; }
            __syncthreads();
            if (tid == 0) {
                resC[s] = dred[0] + dred[1] + dred[2] + dred[3];
                resS[s] = dred[4] + dred[5] + dred[6] + dred[7];
            }
        }
        __syncthreads();
        if (tid == 0) {
            const double wgt[5] = {0.0448, 0.2856, 0.3001, 0.2363, 0.1333};
            double ms = 1.0;
            for (int s = 0; s < 5; ++s) {
                int Hs = 512 >> s;
                double cnt = (double)NIMG * (double)(Hs - 10) * (double)(Hs - 10);
                double cs = resC[s] / cnt;
                double sv = resS[s] / cnt;
                if (cs < 0.0) cs = 0.0;
                if (sv < 0.0) sv = 0.0;
                cs = (cs + 1.0) * 0.5;
                sv = (sv + 1.0) * 0.5;
                ms *= pow((s < 4) ? cs : sv, wgt[s]);
            }
            out[0] = (float)(1.0 - ms);
        }
    }
}

// ---------------------------------------------------------------------------
extern "C" void kernel_launch(void* const* d_in, const int* in_sizes, int n_in,
                              void* d_out, int out_size, void* d_ws, size_t ws_size,
                              hipStream_t stream) {
    (void)in_sizes; (void)n_in; (void)out_size; (void)ws_size;
    const float* A0 = (const float*)d_in[0];
    const float* B0 = (const float*)d_in[1];
    float* out = (float*)d_out;
    unsigned char* ws = (unsigned char*)d_ws;

    // zero the barrier control words (ws is re-poisoned before every launch)
    (void)hipMemsetAsync(ws, 0, 256, stream);
    ms_ssim_all<<<NBLK, 256, 0, stream>>>(A0, B0, out, ws);
}